// Round 11
// baseline (472.069 us; speedup 1.0000x reference)
//
#include <hip/hip_runtime.h>
#include <hip/hip_bf16.h>

// CrossBandWindowAttentionWav — R11 = R10 + counted-vmcnt deep pipeline (T4).
// gws4_k: BM=64/BN=64/BK=32, 3-buffer LDS (24KB, 6 blocks/CU), depth-2
// prefetch: issue tile t+2 after a RAW s_barrier; per-wave s_waitcnt
// vmcnt(3|2) keeps newer loads in flight across barriers (never drain to 0
// in the main loop). fp32 A double-buffers staging regs (t&1). LDS layout,
// epilogues, attn, prep identical to R10 (passed, conflicts=0).

typedef __attribute__((ext_vector_type(8))) short short8;
typedef __attribute__((ext_vector_type(4))) float f32x4;

__device__ __forceinline__ f32x4 mfma_b16(short8 a, short8 b, f32x4 c) {
  return __builtin_amdgcn_mfma_f32_16x16x32_bf16(a, b, c, 0, 0, 0);
}

__device__ __forceinline__ unsigned short f2bf(float x) {
  return __builtin_bit_cast(unsigned short, __float2bfloat16(x));  // RNE
}

__device__ __forceinline__ unsigned pack2(float a, float b) {
  return (unsigned)f2bf(a) | ((unsigned)f2bf(b) << 16);
}

// packed-pair LDS addr: row r (64B of K=32 bf16), chunk c (16B). Two rows
// per 128B line; slot = ((r&1)*4 | c) ^ ((r>>1)&7).  (R10-proven, 0 conflicts)
__device__ __forceinline__ int lds_addr(int r, int c) {
  return (r >> 1) * 128 + (((((r & 1) << 2) | c) ^ ((r >> 1) & 7)) << 4);
}

__device__ __forceinline__ void gl_lds16(const char* g, char* l) {
  __builtin_amdgcn_global_load_lds(
      (const __attribute__((address_space(1))) unsigned int*)g,
      (__attribute__((address_space(3))) unsigned int*)l, 16, 0, 0);
}

#define WAITV3 asm volatile("s_waitcnt vmcnt(3) lgkmcnt(0)" ::: "memory")
#define WAITV2 asm volatile("s_waitcnt vmcnt(2) lgkmcnt(0)" ::: "memory")
#define WAITV0 asm volatile("s_waitcnt vmcnt(0) lgkmcnt(0)" ::: "memory")
#define SBAR                            \
  __builtin_amdgcn_sched_barrier(0);    \
  __builtin_amdgcn_s_barrier();         \
  __builtin_amdgcn_sched_barrier(0)

// ---------------------------------------------------------------- prep ------
// Wq_t padded to 128 rows, Wkv_t padded to 512 rows (zeros beyond real N).
__global__ void prep_k(const float* __restrict__ Wq, const float* __restrict__ Wk,
                       const float* __restrict__ Wv, const float* __restrict__ Wp,
                       const float* __restrict__ rpb, const int* __restrict__ rpi,
                       const float* __restrict__ bk, const float* __restrict__ bv,
                       unsigned short* __restrict__ Wq_t, unsigned short* __restrict__ Wkv_t,
                       unsigned short* __restrict__ Wp_t, float* __restrict__ bias6,
                       float* __restrict__ bias_kv) {
  const int T0 = 128 * 384, T1 = 512 * 384, T2 = 384 * 384, T3 = 6 * 4096, T4 = 480;
  int total = T0 + T1 + T2 + T3 + T4;
  for (int i = blockIdx.x * blockDim.x + threadIdx.x; i < total;
       i += gridDim.x * blockDim.x) {
    int r = i;
    if (r < T0) {                       // Wq_t[n][k] = Wq[k][n], n<96 else 0
      int n = r / 384, k = r % 384;
      Wq_t[r] = (n < 96) ? f2bf(Wq[k * 96 + n]) : (unsigned short)0;
    } else if ((r -= T0) < T1) {        // 0..95 Wk^T, 96..479 Wv^T, else 0
      int n = r / 384, k = r % 384;
      Wkv_t[r] = (n < 96) ? f2bf(Wk[k * 96 + n])
                          : (n < 480) ? f2bf(Wv[k * 384 + (n - 96)])
                                      : (unsigned short)0;
    } else if ((r -= T1) < T2) {
      int n = r / 384, k = r % 384;
      Wp_t[r] = f2bf(Wp[k * 384 + n]);
    } else if ((r -= T2) < T3) {        // bias6[h][i][j] = rpb[rpi[i][j]][h]
      int h = r >> 12, ij = r & 4095;
      bias6[r] = rpb[rpi[ij] * 6 + h];
    } else {
      r -= T3;
      bias_kv[r] = (r < 96) ? bk[r] : bv[r - 96];
    }
  }
}

// ---------------------------------------------------------------- GEMM ------
// C[M=131072, N=NX*64] = A[M,384] @ Bt[N,384]^T + bias.  BM=64 BN=64 BK=32.
// grid = NX*2048 XCD-swizzled. LDS 24KB: A 3x4K @0, B 3x4K @12288.
// Depth-2 counted pipeline; per-phase VMEM per wave: fp32 A = {A0,A1 flat,
// B gl_lds} (wait vmcnt(3)); bf16 A = {A gl_lds, B gl_lds} (wait vmcnt(2)).
// OUT 0: bf16 [M,96], cols>=96 dropped | 1: fp32 [M,384] | 2: col<96 ->
// k_out[M,96]; 96<=col<480 -> vt_out (win,d,tok) chunk-swizzled bf16.
template <int A_F32, int OUT_MODE, int NX>
__global__ __launch_bounds__(256, 6) void gws4_k(
    const void* __restrict__ Av, const unsigned short* __restrict__ Bt,
    const float* __restrict__ bias, void* __restrict__ Outv,
    unsigned short* __restrict__ k_out, unsigned short* __restrict__ vt_out) {
  __shared__ char lds[24576];
  const int tid = threadIdx.x, lane = tid & 63, wid = tid >> 6;
  const int lr = lane & 15, lg = lane >> 4;
  const int g = blockIdx.x;
  const int lg_id = (g & 7) * (NX * 256) + (g >> 3);
  const int my = lg_id / NX, nx = lg_id - my * NX;
  const int m0 = my * 64, n0 = nx * 64;
  const int wm = (wid >> 1) * 32, wn = (wid & 1) * 32;

  // gl_lds inverse slot map (R10-proven): wave writes lines wid*8.. linearly.
  const int L = wid * 8 + (lane >> 3);
  const int sh = (lane & 7) ^ (L & 7);
  const int g_row = L * 2 + ((sh >> 2) & 1);
  const int g_c = sh & 3;

  const int ar = tid >> 2, ac = tid & 3;  // fp32-A staging: row, chunk
  float4 ae0, ae1, ao0, ao1;              // even/odd tile staging regs

  auto issueB = [&](int kt, int b) {
    gl_lds16((const char*)Bt + (size_t)(n0 + g_row) * 768 + kt * 64 + g_c * 16,
             lds + 12288 + b * 4096 + wid * 1024);
  };
  auto issueA8 = [&](int kt, int b) {
    gl_lds16((const char*)Av + (size_t)(m0 + g_row) * 768 + kt * 64 + g_c * 16,
             lds + b * 4096 + wid * 1024);
  };
  auto issueAf = [&](int kt, float4& r0, float4& r1) {
    const float* A = (const float*)Av + (size_t)(m0 + ar) * 384 + kt * 32 + ac * 8;
    r0 = *reinterpret_cast<const float4*>(A);
    r1 = *reinterpret_cast<const float4*>(A + 4);
  };
  auto awrite = [&](int b, const float4& r0, const float4& r1) {
    uint4 pk;
    pk.x = pack2(r0.x, r0.y);
    pk.y = pack2(r0.z, r0.w);
    pk.z = pack2(r1.x, r1.y);
    pk.w = pack2(r1.z, r1.w);
    *reinterpret_cast<uint4*>(lds + b * 4096 + lds_addr(ar, ac)) = pk;
  };

  f32x4 acc[2][2];
#pragma unroll
  for (int i = 0; i < 2; ++i)
#pragma unroll
    for (int j = 0; j < 2; ++j) acc[i][j] = (f32x4){0.f, 0.f, 0.f, 0.f};

  auto comp = [&](int b) {
    const char* Ab = lds + b * 4096;
    const char* Bb = lds + 12288 + b * 4096;
    const short8 a0 = *reinterpret_cast<const short8*>(Ab + lds_addr(wm + lr, lg));
    const short8 a1 = *reinterpret_cast<const short8*>(Ab + lds_addr(wm + 16 + lr, lg));
    const short8 b0 = *reinterpret_cast<const short8*>(Bb + lds_addr(wn + lr, lg));
    const short8 b1 = *reinterpret_cast<const short8*>(Bb + lds_addr(wn + 16 + lr, lg));
    acc[0][0] = mfma_b16(a0, b0, acc[0][0]);
    acc[0][1] = mfma_b16(a0, b1, acc[0][1]);
    acc[1][0] = mfma_b16(a1, b0, acc[1][0]);
    acc[1][1] = mfma_b16(a1, b1, acc[1][1]);
  };

  // prologue: tiles 0 (even regs) and 1 (odd regs); queue order A,A,B | A,A,B
  if (A_F32) {
    issueAf(0, ae0, ae1);
    issueB(0, 0);
    issueAf(1, ao0, ao1);
    issueB(1, 1);
    awrite(0, ae0, ae1);  // compiler waits ae's vmcnt here
  } else {
    issueA8(0, 0);
    issueB(0, 0);
    issueA8(1, 1);
    issueB(1, 1);
  }

#pragma unroll
  for (int t = 0; t < 12; ++t) {
    if (t < 11) {
      if (A_F32) WAITV3; else WAITV2;   // tile t fully landed; t+1 in flight
    } else {
      WAITV0;
    }
    SBAR;
    if (t < 10) {                        // issue tile t+2 (stays in flight)
      if (A_F32) {
        if (t & 1) issueAf(t + 2, ao0, ao1); else issueAf(t + 2, ae0, ae1);
        issueB(t + 2, (t + 2) % 3);
      } else {
        issueA8(t + 2, (t + 2) % 3);
        issueB(t + 2, (t + 2) % 3);
      }
    }
    comp(t % 3);
    if (A_F32 && t < 11) {               // stage tile t+1's A into LDS
      if (t & 1) awrite((t + 1) % 3, ae0, ae1);
      else awrite((t + 1) % 3, ao0, ao1);
    }
  }

  // ---- epilogue: row = m0+wm+mf*16+lg*4+r, col = n0+wn+nf*16+lr (R10)
#pragma unroll
  for (int mf = 0; mf < 2; ++mf)
#pragma unroll
    for (int nf = 0; nf < 2; ++nf) {
      const int col = n0 + wn + nf * 16 + lr;
      if (OUT_MODE == 0) {
        if (col < 96) {
          const float bb = bias[col];
#pragma unroll
          for (int r = 0; r < 4; ++r) {
            const int row = m0 + wm + mf * 16 + lg * 4 + r;
            ((unsigned short*)Outv)[(size_t)row * 96 + col] = f2bf(acc[mf][nf][r] + bb);
          }
        }
      } else if (OUT_MODE == 1) {
        const float bb = bias[col];
#pragma unroll
        for (int r = 0; r < 4; ++r) {
          const int row = m0 + wm + mf * 16 + lg * 4 + r;
          ((float*)Outv)[(size_t)row * 384 + col] = acc[mf][nf][r] + bb;
        }
      } else {
        if (col < 96) {
          const float bb = bias[col];
#pragma unroll
          for (int r = 0; r < 4; ++r) {
            const int row = m0 + wm + mf * 16 + lg * 4 + r;
            k_out[(size_t)row * 96 + col] = f2bf(acc[mf][nf][r] + bb);
          }
        } else if (col < 480) {
          const float bb = bias[col];
          const int d = col - 96;
          const int tok0 = wm + mf * 16 + lg * 4;
          uint2 st;
          st.x = pack2(acc[mf][nf][0] + bb, acc[mf][nf][1] + bb);
          st.y = pack2(acc[mf][nf][2] + bb, acc[mf][nf][3] + bb);
          const int c = tok0 >> 3;
          *reinterpret_cast<uint2*>((char*)vt_out + (size_t)my * 49152 + d * 128 +
                                    ((c ^ (d & 7)) << 4) + ((tok0 * 2) & 8)) = st;
        }
      }
    }
}

// ----------------------------------------------------------- attention ------
// 1 block = 1 window, 4 waves; wave handles 16 query rows (iq = wid*16+lr).
// Swapped-operand QK^T and PV; softmax fully in-register (shfl 16/32).
__global__ __launch_bounds__(256, 2) void attn_k(
    const unsigned short* __restrict__ q_buf, const unsigned short* __restrict__ k_buf,
    const unsigned short* __restrict__ vt_buf, const float* __restrict__ bias6,
    const float* __restrict__ mask, unsigned short* __restrict__ att_buf) {
  __shared__ char lds[57344];  // vt [384][128B] swz @0; P [64][128B] swz @49152
  const int tid = threadIdx.x, lane = tid & 63, wid = tid >> 6;
  const int lr = lane & 15, lg = lane >> 4;
  const int w = blockIdx.x;

  const char* vsrc = (const char*)vt_buf + (size_t)w * 49152;  // pre-swizzled
#pragma unroll
  for (int j = 0; j < 12; ++j) {
    const int off = (wid * 12 + j) * 1024;
    gl_lds16(vsrc + off + lane * 16, lds + off);
  }
  __syncthreads();

  char* Plds = lds + 49152;
  const float* mw = mask + (size_t)(w & 1023) * 4096;
  const int iq = wid * 16 + lr;  // this lane's query row

  for (int h = 0; h < 6; ++h) {
    // S^T = mfma(K, Q): lane gets S[j][iq], j = tj*16 + lg*4 + r
    short8 qa = {0, 0, 0, 0, 0, 0, 0, 0};
    if (lg < 2)
      qa = *reinterpret_cast<const short8*>(
          q_buf + (size_t)(w * 64 + iq) * 96 + h * 16 + lg * 8);
    float sv[4][4];
#pragma unroll
    for (int tj = 0; tj < 4; ++tj) {
      short8 kf = {0, 0, 0, 0, 0, 0, 0, 0};
      if (lg < 2)
        kf = *reinterpret_cast<const short8*>(
            k_buf + (size_t)(w * 64 + tj * 16 + lr) * 96 + h * 16 + lg * 8);
      f32x4 z = {0.f, 0.f, 0.f, 0.f};
      f32x4 s = mfma_b16(kf, qa, z);
      const int j0 = tj * 16 + lg * 4;
      const float4 bi = *reinterpret_cast<const float4*>(bias6 + h * 4096 + iq * 64 + j0);
      const float4 mk = *reinterpret_cast<const float4*>(mw + iq * 64 + j0);
      sv[tj][0] = s[0] * 0.25f + bi.x + mk.x;
      sv[tj][1] = s[1] * 0.25f + bi.y + mk.y;
      sv[tj][2] = s[2] * 0.25f + bi.z + mk.z;
      sv[tj][3] = s[3] * 0.25f + bi.w + mk.w;
    }
    float mx = sv[0][0];
#pragma unroll
    for (int tj = 0; tj < 4; ++tj)
#pragma unroll
      for (int r = 0; r < 4; ++r) mx = fmaxf(mx, sv[tj][r]);
    mx = fmaxf(mx, __shfl_xor(mx, 16));
    mx = fmaxf(mx, __shfl_xor(mx, 32));
    float sum = 0.f;
#pragma unroll
    for (int tj = 0; tj < 4; ++tj)
#pragma unroll
      for (int r = 0; r < 4; ++r) {
        sv[tj][r] = __expf(sv[tj][r] - mx);
        sum += sv[tj][r];
      }
    sum += __shfl_xor(sum, 16);
    sum += __shfl_xor(sum, 32);
    const float inv = 1.0f / sum;
    // P row iq -> LDS (swizzled); written & read by this wave only
#pragma unroll
    for (int tj = 0; tj < 4; ++tj) {
      const int c = tj * 2 + (lg >> 1);
      uint2 st;
      st.x = pack2(sv[tj][0] * inv, sv[tj][1] * inv);
      st.y = pack2(sv[tj][2] * inv, sv[tj][3] * inv);
      *reinterpret_cast<uint2*>(Plds + iq * 128 + ((c ^ (iq & 7)) << 4) +
                                (lg & 1) * 8) = st;
    }
    short8 pa[2];
#pragma unroll
    for (int ks = 0; ks < 2; ++ks)
      pa[ks] = *reinterpret_cast<const short8*>(
          Plds + iq * 128 + (((ks * 4 + lg) ^ (iq & 7)) << 4));
    // att[iq][d] via mfma(V^T, P): lane gets d = h*64 + td*16 + lg*4 + r
#pragma unroll
    for (int td = 0; td < 4; ++td) {
      f32x4 o = {0.f, 0.f, 0.f, 0.f};
#pragma unroll
      for (int ks = 0; ks < 2; ++ks) {
        const int d = h * 64 + td * 16 + lr;
        short8 vb = *reinterpret_cast<const short8*>(
            lds + d * 128 + (((ks * 4 + lg) ^ (d & 7)) << 4));
        o = mfma_b16(vb, pa[ks], o);
      }
      const int c0 = h * 64 + td * 16 + lg * 4;
      uint2 st;
      st.x = pack2(o[0], o[1]);
      st.y = pack2(o[2], o[3]);
      // LINEAR att layout [tok][384] bf16 (proj stages it via gl_lds)
      *reinterpret_cast<uint2*>((char*)att_buf + (size_t)(w * 64 + iq) * 768 +
                                c0 * 2) = st;
    }
  }
}

// -------------------------------------------------------------- launch ------
extern "C" void kernel_launch(void* const* d_in, const int* in_sizes, int n_in,
                              void* d_out, int out_size, void* d_ws, size_t ws_size,
                              hipStream_t stream) {
  const float* x    = (const float*)d_in[0];
  const float* cx   = (const float*)d_in[1];
  const int*   rpi  = (const int*)d_in[2];
  const float* mask = (const float*)d_in[3];
  const float* Wq   = (const float*)d_in[4];
  const float* bq   = (const float*)d_in[5];
  const float* Wk   = (const float*)d_in[6];
  const float* bk   = (const float*)d_in[7];
  const float* Wv   = (const float*)d_in[8];
  const float* bv   = (const float*)d_in[9];
  const float* Wp   = (const float*)d_in[10];
  const float* bp   = (const float*)d_in[11];
  const float* rpb  = (const float*)d_in[12];

  char* ws = (char*)d_ws;
  unsigned short* Wq_t   = (unsigned short*)(ws + 0);        //  98,304 B (128x384)
  unsigned short* Wkv_t  = (unsigned short*)(ws + 98304);    // 393,216 B (512x384)
  unsigned short* Wp_t   = (unsigned short*)(ws + 491520);   // 294,912 B
  float*          bias6  = (float*)(ws + 786432);            //  98,304 B
  float*          biaskv = (float*)(ws + 884736);            //   1,920 B
  const size_t MB = 1u << 20;
  unsigned short* q_buf  = (unsigned short*)(ws + MB);                   // 25,165,824 B
  unsigned short* k_buf  = (unsigned short*)(ws + MB + 25165824u);       // 25,165,824 B
  unsigned short* vt_buf = (unsigned short*)(ws + MB + 50331648u);       // 100,663,296 B
  unsigned short* att    = (unsigned short*)(ws + MB + 150994944u);      // 100,663,296 B

  prep_k<<<256, 256, 0, stream>>>(Wq, Wk, Wv, Wp, rpb, rpi, bk, bv,
                                  Wq_t, Wkv_t, Wp_t, bias6, biaskv);
  gws4_k<1, 0, 2><<<4096, 256, 0, stream>>>(x, Wq_t, bq, q_buf, nullptr, nullptr);
  gws4_k<1, 2, 8><<<16384, 256, 0, stream>>>(cx, Wkv_t, biaskv, nullptr, k_buf, vt_buf);
  attn_k<<<2048, 256, 0, stream>>>(q_buf, k_buf, vt_buf, bias6, mask, att);
  gws4_k<0, 1, 6><<<12288, 256, 0, stream>>>(att, Wp_t, bp, d_out, nullptr, nullptr);
}

// Round 12
// 348.076 us; speedup vs baseline: 1.3562x; 1.3562x over previous
//
#include <hip/hip_runtime.h>
#include <hip/hip_bf16.h>

// CrossBandWindowAttentionWav — R12: R6 GEMMs + fused attention+projection.
// prep -> gemm3 q -> gemm3 k|v (vt now PRE-SWIZZLED chunks) -> ap_k
// (per-window: vt via global_load_lds, swapped QK/PV attn with in-reg
// softmax, att stashed in regs -> spilled to LDS swz48 -> proj with
// B-dbuf gl_lds and zero A staging -> fp32 out). att never touches HBM.

typedef __attribute__((ext_vector_type(8))) short short8;
typedef __attribute__((ext_vector_type(4))) float f32x4;

__device__ __forceinline__ f32x4 mfma_b16(short8 a, short8 b, f32x4 c) {
  return __builtin_amdgcn_mfma_f32_16x16x32_bf16(a, b, c, 0, 0, 0);
}

__device__ __forceinline__ unsigned short f2bf(float x) {
  return __builtin_bit_cast(unsigned short, __float2bfloat16(x));  // RNE
}

__device__ __forceinline__ unsigned pack2(float a, float b) {
  return (unsigned)f2bf(a) | ((unsigned)f2bf(b) << 16);
}

// chunk swizzle for 768B rows (48 x 16B chunks): XOR low3 of chunk with row
__device__ __forceinline__ int swz48(int c, int r) {
  return (c & ~7) | ((c ^ r) & 7);
}

__device__ __forceinline__ void gl_lds16(const char* g, char* l) {
  __builtin_amdgcn_global_load_lds(
      (const __attribute__((address_space(1))) unsigned int*)g,
      (__attribute__((address_space(3))) unsigned int*)l, 16, 0, 0);
}

// ---------------------------------------------------------------- prep ------
__global__ void prep_k(const float* __restrict__ Wq, const float* __restrict__ Wk,
                       const float* __restrict__ Wv, const float* __restrict__ Wp,
                       const float* __restrict__ rpb, const int* __restrict__ rpi,
                       const float* __restrict__ bk, const float* __restrict__ bv,
                       unsigned short* __restrict__ Wq_t, unsigned short* __restrict__ Wkv_t,
                       unsigned short* __restrict__ Wp_t, float* __restrict__ bias6,
                       float* __restrict__ bias_kv) {
  const int T0 = 96 * 384, T1 = 480 * 384, T2 = 384 * 384, T3 = 6 * 4096, T4 = 480;
  int total = T0 + T1 + T2 + T3 + T4;
  for (int i = blockIdx.x * blockDim.x + threadIdx.x; i < total;
       i += gridDim.x * blockDim.x) {
    int r = i;
    if (r < T0) {                       // Wq_t[n][k] = Wq[k][n]
      int n = r / 384, k = r % 384;
      Wq_t[r] = f2bf(Wq[k * 96 + n]);
    } else if ((r -= T0) < T1) {        // rows 0..95 = Wk^T, 96..479 = Wv^T
      int n = r / 384, k = r % 384;
      Wkv_t[r] = f2bf(n < 96 ? Wk[k * 96 + n] : Wv[k * 384 + (n - 96)]);
    } else if ((r -= T1) < T2) {
      int n = r / 384, k = r % 384;
      Wp_t[r] = f2bf(Wp[k * 384 + n]);
    } else if ((r -= T2) < T3) {        // bias6[h][i][j] = rpb[rpi[i][j]][h]
      int h = r >> 12, ij = r & 4095;
      bias6[r] = rpb[rpi[ij] * 6 + h];
    } else {
      r -= T3;
      bias_kv[r] = (r < 96) ? bk[r] : bv[r - 96];
    }
  }
}

// ---------------------------------------------------------------- GEMM ------
// R6's proven gemm3_k. C[M=131072, N=NX*96] = A[M,384] @ Bt[N,384]^T + bias.
// BM=64 BN=96 BK=64, 40KB LDS dbuf, 4 blocks/CU, XCD-bijective swizzle.
// OUT_MODE 0: bf16 [M,96] | 2: nx==0 -> k_out[M,96]; nx>=1 -> vt_out
// (win,d,tok) bf16 with PRE-SWIZZLED 16B chunks (c ^ (d&7)).
template <int A_MODE, int OUT_MODE, int NX>
__global__ __launch_bounds__(256, 4) void gemm3_k(
    const void* __restrict__ Av, const unsigned short* __restrict__ Bt,
    const float* __restrict__ bias, void* __restrict__ Outv,
    unsigned short* __restrict__ k_out, unsigned short* __restrict__ vt_out) {
  __shared__ char lds[40960];  // A: 2x8KB @0, B: 2x12KB @16384
  constexpr int AB[2] = {0, 8192}, BB[2] = {16384, 28672};
  const int tid = threadIdx.x, lane = tid & 63, wid = tid >> 6;
  const int g = blockIdx.x;
  const int lg_id = (g & 7) * (NX * 256) + (g >> 3);
  const int my = lg_id / NX, nx = lg_id - my * NX;
  const int m0 = my * 64, n0 = nx * 96;
  const int wm = (wid >> 1) * 32, wn = (wid & 1) * 48;
  const int lr = lane & 15, lg = lane >> 4;

  float4 areg[4];
  const int ar = tid >> 2, aq = tid & 3;  // fp32-A staging: row, quarter

  auto a_issue_f32 = [&](int kt) {
    const float* A = (const float*)Av + (size_t)(m0 + ar) * 384 + kt * 64 + aq * 16;
#pragma unroll
    for (int p = 0; p < 4; ++p) areg[p] = *reinterpret_cast<const float4*>(A + p * 4);
  };
  auto a_write_f32 = [&](char* Ab) {
    unsigned pk[8];
#pragma unroll
    for (int p = 0; p < 4; ++p) {
      pk[p * 2]     = pack2(areg[p].x, areg[p].y);
      pk[p * 2 + 1] = pack2(areg[p].z, areg[p].w);
    }
    const int c0 = aq * 2;
    *reinterpret_cast<uint4*>(Ab + ar * 128 + ((c0 ^ (ar & 7)) * 16)) =
        make_uint4(pk[0], pk[1], pk[2], pk[3]);
    *reinterpret_cast<uint4*>(Ab + ar * 128 + (((c0 + 1) ^ (ar & 7)) * 16)) =
        make_uint4(pk[4], pk[5], pk[6], pk[7]);
  };
  auto b_issue = [&](int kt, char* Bb) {
#pragma unroll
    for (int j = 0; j < 3; ++j) {
      const int rb = (wid * 3 + j) * 8;
      const int row = rb + (lane >> 3), c = lane & 7;
      gl_lds16((const char*)Bt + (size_t)(n0 + row) * 768 + kt * 128 +
                   ((c ^ (row & 7)) * 16),
               Bb + rb * 128);
    }
  };

  f32x4 acc[2][3];
#pragma unroll
  for (int i = 0; i < 2; ++i)
#pragma unroll
    for (int j = 0; j < 3; ++j) acc[i][j] = (f32x4){0.f, 0.f, 0.f, 0.f};

  a_issue_f32(0);
  a_write_f32(lds + AB[0]);
  b_issue(0, lds + BB[0]);
  __syncthreads();

  int cur = 0;
  for (int kt = 0; kt < 6; ++kt) {
    char* An = lds + AB[cur ^ 1];
    char* Bn = lds + BB[cur ^ 1];
    if (kt < 5) {
      a_issue_f32(kt + 1);
      b_issue(kt + 1, Bn);
    }
    {
      const char* Ab = lds + AB[cur];
      const char* Bb = lds + BB[cur];
#pragma unroll
      for (int ks = 0; ks < 2; ++ks) {
        short8 a[2], b[3];
#pragma unroll
        for (int mf = 0; mf < 2; ++mf) {
          const int row = wm + mf * 16 + lr;
          a[mf] = *reinterpret_cast<const short8*>(
              Ab + row * 128 + (((ks * 4 + lg) ^ (row & 7)) * 16));
        }
#pragma unroll
        for (int nf = 0; nf < 3; ++nf) {
          const int row = wn + nf * 16 + lr;
          b[nf] = *reinterpret_cast<const short8*>(
              Bb + row * 128 + (((ks * 4 + lg) ^ (row & 7)) * 16));
        }
#pragma unroll
        for (int mf = 0; mf < 2; ++mf)
#pragma unroll
          for (int nf = 0; nf < 3; ++nf)
            acc[mf][nf] = mfma_b16(a[mf], b[nf], acc[mf][nf]);
      }
    }
    if (kt < 5) a_write_f32(An);
    __syncthreads();
    cur ^= 1;
  }

  // ---- epilogues
  if (OUT_MODE == 0 || (OUT_MODE == 2 && nx == 0)) {  // bf16 [M,96], pad 208
    unsigned short* dst = (OUT_MODE == 0) ? (unsigned short*)Outv : k_out;
#pragma unroll
    for (int mf = 0; mf < 2; ++mf)
#pragma unroll
      for (int nf = 0; nf < 3; ++nf) {
        const int col = wn + nf * 16 + lr;
        const float bb = bias[col];
#pragma unroll
        for (int r = 0; r < 4; ++r) {
          const int row = wm + mf * 16 + lg * 4 + r;
          *reinterpret_cast<unsigned short*>(lds + row * 208 + col * 2) =
              f2bf(acc[mf][nf][r] + bb);
        }
      }
    __syncthreads();
#pragma unroll
    for (int j = 0; j < 3; ++j) {
      const int Lb = (j * 256 + tid) * 16;
      const int row = Lb / 192, inner = Lb % 192;
      *reinterpret_cast<uint4*>((char*)dst + (size_t)(m0 + row) * 192 + inner) =
          *reinterpret_cast<const uint4*>(lds + row * 208 + inner);
    }
  } else {  // vt: transpose to (win=my, d, tok), PRE-SWIZZLED chunks
#pragma unroll
    for (int mf = 0; mf < 2; ++mf)
#pragma unroll
      for (int nf = 0; nf < 3; ++nf) {
        const int dl = wn + nf * 16 + lr;
        const float bb = bias[n0 + dl];
        const int tok0 = wm + mf * 16 + lg * 4;
        *reinterpret_cast<unsigned*>(lds + dl * 144 + tok0 * 2) =
            pack2(acc[mf][nf][0] + bb, acc[mf][nf][1] + bb);
        *reinterpret_cast<unsigned*>(lds + dl * 144 + tok0 * 2 + 4) =
            pack2(acc[mf][nf][2] + bb, acc[mf][nf][3] + bb);
      }
    __syncthreads();
#pragma unroll
    for (int j = 0; j < 3; ++j) {
      const int Lc = j * 256 + tid;  // 16B chunk id, 768 total
      const int dl = Lc >> 3, c = Lc & 7;
      *reinterpret_cast<uint4*>((char*)vt_out + (size_t)my * 49152 +
                                (size_t)((nx - 1) * 96 + dl) * 128 +
                                ((c ^ (dl & 7)) << 4)) =
          *reinterpret_cast<const uint4*>(lds + dl * 144 + c * 16);
    }
  }
}

// ------------------------------------------- fused attention + proj ---------
// 1 block = 1 window, 4 waves. LDS: vt 48KB @0 (att overlays after attn);
// P @49152 (8KB); proj B dbuf @57344 (2x12KB). 80KB total, 2 blocks/CU.
__global__ __launch_bounds__(256, 2) void ap_k(
    const unsigned short* __restrict__ q_buf, const unsigned short* __restrict__ k_buf,
    const unsigned short* __restrict__ vt_buf, const float* __restrict__ bias6,
    const float* __restrict__ mask, const unsigned short* __restrict__ Wp_t,
    const float* __restrict__ bp, float* __restrict__ out) {
  __shared__ char lds[81920];
  const int tid = threadIdx.x, lane = tid & 63, wid = tid >> 6;
  const int lr = lane & 15, lg = lane >> 4;
  const int w = blockIdx.x;

  auto b_issue = [&](int T, char* Bb) {  // T = nc*6+kt over Wp_t
    const int nc = T / 6, kt = T - nc * 6;
#pragma unroll
    for (int j = 0; j < 3; ++j) {
      const int rb = (wid * 3 + j) * 8;
      const int row = rb + (lane >> 3), c = lane & 7;
      gl_lds16((const char*)Wp_t + (size_t)(nc * 96 + row) * 768 + kt * 128 +
                   ((c ^ (row & 7)) * 16),
               Bb + rb * 128);
    }
  };

  // stage vt (pre-swizzled) + prefetch proj B tiles 0,1
  const char* vsrc = (const char*)vt_buf + (size_t)w * 49152;
#pragma unroll
  for (int j = 0; j < 12; ++j) {
    const int off = (wid * 12 + j) * 1024;
    gl_lds16(vsrc + off + lane * 16, lds + off);
  }
  b_issue(0, lds + 57344);
  b_issue(1, lds + 57344 + 12288);
  __syncthreads();

  // ---- attention (R10-proven math); att -> stash regs
  unsigned stash[48];
  char* Plds = lds + 49152;
  const float* mw = mask + (size_t)(w & 1023) * 4096;
  const int iq = wid * 16 + lr;

  for (int h = 0; h < 6; ++h) {
    short8 qa = {0, 0, 0, 0, 0, 0, 0, 0};
    if (lg < 2)
      qa = *reinterpret_cast<const short8*>(
          q_buf + (size_t)(w * 64 + iq) * 96 + h * 16 + lg * 8);
    float sv[4][4];
#pragma unroll
    for (int tj = 0; tj < 4; ++tj) {
      short8 kf = {0, 0, 0, 0, 0, 0, 0, 0};
      if (lg < 2)
        kf = *reinterpret_cast<const short8*>(
            k_buf + (size_t)(w * 64 + tj * 16 + lr) * 96 + h * 16 + lg * 8);
      f32x4 z = {0.f, 0.f, 0.f, 0.f};
      f32x4 s = mfma_b16(kf, qa, z);
      const int j0 = tj * 16 + lg * 4;
      const float4 bi = *reinterpret_cast<const float4*>(bias6 + h * 4096 + iq * 64 + j0);
      const float4 mk = *reinterpret_cast<const float4*>(mw + iq * 64 + j0);
      sv[tj][0] = s[0] * 0.25f + bi.x + mk.x;
      sv[tj][1] = s[1] * 0.25f + bi.y + mk.y;
      sv[tj][2] = s[2] * 0.25f + bi.z + mk.z;
      sv[tj][3] = s[3] * 0.25f + bi.w + mk.w;
    }
    float mx = sv[0][0];
#pragma unroll
    for (int tj = 0; tj < 4; ++tj)
#pragma unroll
      for (int r = 0; r < 4; ++r) mx = fmaxf(mx, sv[tj][r]);
    mx = fmaxf(mx, __shfl_xor(mx, 16));
    mx = fmaxf(mx, __shfl_xor(mx, 32));
    float sum = 0.f;
#pragma unroll
    for (int tj = 0; tj < 4; ++tj)
#pragma unroll
      for (int r = 0; r < 4; ++r) {
        sv[tj][r] = __expf(sv[tj][r] - mx);
        sum += sv[tj][r];
      }
    sum += __shfl_xor(sum, 16);
    sum += __shfl_xor(sum, 32);
    const float inv = 1.0f / sum;
#pragma unroll
    for (int tj = 0; tj < 4; ++tj) {
      const int c = tj * 2 + (lg >> 1);
      uint2 st;
      st.x = pack2(sv[tj][0] * inv, sv[tj][1] * inv);
      st.y = pack2(sv[tj][2] * inv, sv[tj][3] * inv);
      *reinterpret_cast<uint2*>(Plds + iq * 128 + ((c ^ (iq & 7)) << 4) +
                                (lg & 1) * 8) = st;
    }
    short8 pa[2];
#pragma unroll
    for (int ks = 0; ks < 2; ++ks)
      pa[ks] = *reinterpret_cast<const short8*>(
          Plds + iq * 128 + (((ks * 4 + lg) ^ (iq & 7)) << 4));
#pragma unroll
    for (int td = 0; td < 4; ++td) {
      f32x4 o = {0.f, 0.f, 0.f, 0.f};
#pragma unroll
      for (int ks = 0; ks < 2; ++ks) {
        const int d = h * 64 + td * 16 + lr;
        short8 vb = *reinterpret_cast<const short8*>(
            lds + d * 128 + (((ks * 4 + lg) ^ (d & 7)) << 4));
        o = mfma_b16(vb, pa[ks], o);
      }
      stash[h * 8 + td * 2 + 0] = pack2(o[0], o[1]);
      stash[h * 8 + td * 2 + 1] = pack2(o[2], o[3]);
    }
  }
  __syncthreads();  // all vt/P reads done

  // spill att -> LDS [tok][384] bf16, swz48 chunk layout
#pragma unroll
  for (int h = 0; h < 6; ++h)
#pragma unroll
    for (int td = 0; td < 4; ++td)
#pragma unroll
      for (int p2 = 0; p2 < 2; ++p2) {
        const int c0 = h * 64 + td * 16 + lg * 4 + p2 * 2;
        *reinterpret_cast<unsigned*>(
            lds + iq * 768 + swz48(c0 >> 3, iq) * 16 + ((c0 * 2) & 15)) =
            stash[h * 8 + td * 2 + p2];
      }
  __syncthreads();

  // ---- proj: out = att @ Wp^T + bp.  24 tiles (nc,kt), B dbuf, A from LDS.
  const int wm = (wid >> 1) * 32, wn = (wid & 1) * 48;
  f32x4 acc[2][3];
#pragma unroll
  for (int i = 0; i < 2; ++i)
#pragma unroll
    for (int j = 0; j < 3; ++j) acc[i][j] = (f32x4){0.f, 0.f, 0.f, 0.f};

  for (int T = 0; T < 24; ++T) {
    const int nc = T / 6, kt = T - nc * 6;
    if (T >= 1 && T < 23) b_issue(T + 1, lds + 57344 + ((T + 1) & 1) * 12288);
    const char* Bb = lds + 57344 + (T & 1) * 12288;
#pragma unroll
    for (int ks = 0; ks < 2; ++ks) {
      short8 a[2], b[3];
#pragma unroll
      for (int mf = 0; mf < 2; ++mf) {
        const int row = wm + mf * 16 + lr;
        a[mf] = *reinterpret_cast<const short8*>(
            lds + row * 768 + swz48(kt * 8 + ks * 4 + lg, row) * 16);
      }
#pragma unroll
      for (int nf = 0; nf < 3; ++nf) {
        const int row = wn + nf * 16 + lr;
        b[nf] = *reinterpret_cast<const short8*>(
            Bb + row * 128 + (((ks * 4 + lg) ^ (row & 7)) * 16));
      }
#pragma unroll
      for (int mf = 0; mf < 2; ++mf)
#pragma unroll
        for (int nf = 0; nf < 3; ++nf)
          acc[mf][nf] = mfma_b16(a[mf], b[nf], acc[mf][nf]);
    }
    if (kt == 5) {  // epilogue for this nc, then reset acc
#pragma unroll
      for (int mf = 0; mf < 2; ++mf)
#pragma unroll
        for (int nf = 0; nf < 3; ++nf) {
          const int col = nc * 96 + wn + nf * 16 + lr;
          const float bb = bp[col];
#pragma unroll
          for (int r = 0; r < 4; ++r) {
            const int row = wm + mf * 16 + lg * 4 + r;
            out[(size_t)(w * 64 + row) * 384 + col] = acc[mf][nf][r] + bb;
          }
          acc[mf][nf] = (f32x4){0.f, 0.f, 0.f, 0.f};
        }
    }
    __syncthreads();
  }
}

// -------------------------------------------------------------- launch ------
extern "C" void kernel_launch(void* const* d_in, const int* in_sizes, int n_in,
                              void* d_out, int out_size, void* d_ws, size_t ws_size,
                              hipStream_t stream) {
  const float* x    = (const float*)d_in[0];
  const float* cx   = (const float*)d_in[1];
  const int*   rpi  = (const int*)d_in[2];
  const float* mask = (const float*)d_in[3];
  const float* Wq   = (const float*)d_in[4];
  const float* bq   = (const float*)d_in[5];
  const float* Wk   = (const float*)d_in[6];
  const float* bk   = (const float*)d_in[7];
  const float* Wv   = (const float*)d_in[8];
  const float* bv   = (const float*)d_in[9];
  const float* Wp   = (const float*)d_in[10];
  const float* bp   = (const float*)d_in[11];
  const float* rpb  = (const float*)d_in[12];

  char* ws = (char*)d_ws;
  unsigned short* Wq_t   = (unsigned short*)(ws + 0);        //  73,728 B
  unsigned short* Wkv_t  = (unsigned short*)(ws + 73728);    // 368,640 B
  unsigned short* Wp_t   = (unsigned short*)(ws + 442368);   // 294,912 B
  float*          bias6  = (float*)(ws + 737280);            //  98,304 B
  float*          biaskv = (float*)(ws + 835584);            //   1,920 B
  const size_t MB = 1u << 20;
  unsigned short* q_buf  = (unsigned short*)(ws + MB);                   // 25,165,824 B
  unsigned short* k_buf  = (unsigned short*)(ws + MB + 25165824u);       // 25,165,824 B
  unsigned short* vt_buf = (unsigned short*)(ws + MB + 50331648u);       // 100,663,296 B

  prep_k<<<256, 256, 0, stream>>>(Wq, Wk, Wv, Wp, rpb, rpi, bk, bv,
                                  Wq_t, Wkv_t, Wp_t, bias6, biaskv);
  gemm3_k<0, 0, 1><<<2048, 256, 0, stream>>>(x, Wq_t, bq, q_buf, nullptr, nullptr);
  gemm3_k<0, 2, 5><<<10240, 256, 0, stream>>>(cx, Wkv_t, biaskv, nullptr, k_buf, vt_buf);
  ap_k<<<2048, 256, 0, stream>>>(q_buf, k_buf, vt_buf, bias6, mask, Wp_t, bp,
                                 (float*)d_out);
}